// Round 1
// baseline (9484.119 us; speedup 1.0000x reference)
//
#include <hip/hip_runtime.h>

#define T_ 512
#define B_ 64
#define I_ 256
#define H_ 1024
#define G4_ 4096
#define O_ 256

typedef short bfrag8 __attribute__((ext_vector_type(8)));   // 8 bf16 (4 VGPRs)
typedef float f32x4 __attribute__((ext_vector_type(4)));

// f32 -> bf16 bits, round-to-nearest-even
__device__ __forceinline__ unsigned short f2bf(float f) {
    unsigned int u = __builtin_bit_cast(unsigned int, f);
    u = (u + 0x7fffu + ((u >> 16) & 1u)) >> 16;
    return (unsigned short)u;
}

__global__ void cvt_bf16(const float* __restrict__ in, unsigned short* __restrict__ out, int n) {
    int i = blockIdx.x * blockDim.x + threadIdx.x;
    int st = gridDim.x * blockDim.x;
    for (; i < n; i += st) out[i] = f2bf(in[i]);
}

__global__ void bias_sum_k(const float* __restrict__ a, const float* __restrict__ b,
                           float* __restrict__ o, int n) {
    int i = blockIdx.x * blockDim.x + threadIdx.x;
    if (i < n) o[i] = a[i] + b[i];
}

__device__ __forceinline__ float sigmoidf_(float x) {
    return 1.0f / (1.0f + __expf(-x));
}

// One LSTM time step. Grid: 128 blocks (2 batch-halves x 64 hcol-blocks of 16), 256 threads.
// Wave w (0..3) computes gate w for this block's 16 h-columns over 32 batch rows.
// K is unified: k<1024 -> h_prev @ W_hh slice, k>=1024 -> x_t @ W_ih slice.
__global__ __launch_bounds__(256) void lstm_step(
    const unsigned short* __restrict__ xbf,   // [T][B][I] bf16
    const unsigned short* __restrict__ whh,   // [4H][H] bf16
    const unsigned short* __restrict__ wih,   // [4H][I] bf16
    const float* __restrict__ bsum,           // [4H] = b_ih + b_hh
    unsigned short* __restrict__ hs,          // [T][B][H] bf16
    float* __restrict__ cst,                  // [B][H] f32 cell state
    int t)
{
    const int bid = blockIdx.x;
    const int hcb = bid & 63;          // h-column block (16 cols)
    const int mb  = bid >> 6;          // batch half (32 rows)
    const int tid = threadIdx.x;
    const int w   = tid >> 6;          // wave index == gate index (i,f,g,o)
    const int l   = tid & 63;
    const int l16 = l & 15;
    const int lk8 = (l >> 4) << 3;     // k sub-offset within a 32-K tile

    const int hc0 = hcb * 16;
    const int b0  = mb * 32;
    const int row = w * H_ + hc0 + l16;      // this lane's gate-row (B operand col)

    f32x4 acc0 = {0.f, 0.f, 0.f, 0.f};
    f32x4 acc1 = {0.f, 0.f, 0.f, 0.f};

    if (t > 0) {
        const unsigned short* __restrict__ hprev = hs + (size_t)(t - 1) * (B_ * H_);
        const unsigned short* __restrict__ wrow  = whh + (size_t)row * H_;
        const unsigned short* __restrict__ a0p   = hprev + (size_t)(b0 + l16) * H_;
        const unsigned short* __restrict__ a1p   = hprev + (size_t)(b0 + 16 + l16) * H_;
#pragma unroll 4
        for (int kt = 0; kt < 32; ++kt) {
            int k = kt * 32 + lk8;
            bfrag8 bf = *(const bfrag8*)(wrow + k);
            bfrag8 a0 = *(const bfrag8*)(a0p + k);
            bfrag8 a1 = *(const bfrag8*)(a1p + k);
            acc0 = __builtin_amdgcn_mfma_f32_16x16x32_bf16(a0, bf, acc0, 0, 0, 0);
            acc1 = __builtin_amdgcn_mfma_f32_16x16x32_bf16(a1, bf, acc1, 0, 0, 0);
        }
    }
    {
        const unsigned short* __restrict__ xt   = xbf + (size_t)t * (B_ * I_);
        const unsigned short* __restrict__ wrow = wih + (size_t)row * I_;
        const unsigned short* __restrict__ a0p  = xt + (size_t)(b0 + l16) * I_;
        const unsigned short* __restrict__ a1p  = xt + (size_t)(b0 + 16 + l16) * I_;
#pragma unroll
        for (int kt = 0; kt < 8; ++kt) {
            int k = kt * 32 + lk8;
            bfrag8 bf = *(const bfrag8*)(wrow + k);
            bfrag8 a0 = *(const bfrag8*)(a0p + k);
            bfrag8 a1 = *(const bfrag8*)(a1p + k);
            acc0 = __builtin_amdgcn_mfma_f32_16x16x32_bf16(a0, bf, acc0, 0, 0, 0);
            acc1 = __builtin_amdgcn_mfma_f32_16x16x32_bf16(a1, bf, acc1, 0, 0, 0);
        }
    }

    const float bias = bsum[row];

    // Exchange gate pre-activations: gl[gate][batch(32)][col(16)]
    __shared__ float gl[4][32][16];
    const int mrow = (l >> 4) * 4;     // D row = (lane>>4)*4 + reg  [measured m89/m91]
#pragma unroll
    for (int r = 0; r < 4; ++r) {
        gl[w][mrow + r][l16]      = acc0[r] + bias;
        gl[w][16 + mrow + r][l16] = acc1[r] + bias;
    }
    __syncthreads();

    // Pointwise: 32*16 = 512 (batch,col) pairs; 2 per thread
#pragma unroll
    for (int pp = 0; pp < 2; ++pp) {
        int p = tid + pp * 256;
        int bb = p >> 4;
        int cc = p & 15;
        float ig = sigmoidf_(gl[0][bb][cc]);
        float fg = sigmoidf_(gl[1][bb][cc]);
        float gg = tanhf(gl[2][bb][cc]);
        float og = sigmoidf_(gl[3][bb][cc]);
        int gb  = b0 + bb;
        int ghc = hc0 + cc;
        float cprev = (t > 0) ? cst[gb * H_ + ghc] : 0.0f;
        float cn = fg * cprev + ig * gg;
        cst[gb * H_ + ghc] = cn;
        float hn = og * tanhf(cn);
        hs[(size_t)t * (B_ * H_) + gb * H_ + ghc] = f2bf(hn);
    }
}

// out[TB][256] = hs[TB][1024] @ W_out[256][1024]^T + b_out
// Grid: (32768/64) * (256/64) = 2048 blocks, 256 threads (4 waves).
__global__ __launch_bounds__(256) void out_gemm(
    const unsigned short* __restrict__ hs,
    const unsigned short* __restrict__ wout,
    const float* __restrict__ bout,
    float* __restrict__ out)
{
    const int bid  = blockIdx.x;
    const int nblk = bid & 3;
    const int mblk = bid >> 2;
    const int tid  = threadIdx.x;
    const int w    = tid >> 6;
    const int l    = tid & 63;
    const int l16  = l & 15;
    const int lk8  = (l >> 4) << 3;

    const int m0 = mblk * 64 + w * 16;   // wave's 16 output rows (t*B+b)
    const int n0 = nblk * 64;

    f32x4 acc[4] = {};
    const unsigned short* __restrict__ arow = hs + (size_t)(m0 + l16) * H_;
#pragma unroll 2
    for (int kt = 0; kt < 32; ++kt) {
        int k = kt * 32 + lk8;
        bfrag8 af = *(const bfrag8*)(arow + k);
#pragma unroll
        for (int nt = 0; nt < 4; ++nt) {
            bfrag8 bf = *(const bfrag8*)(wout + (size_t)(n0 + nt * 16 + l16) * H_ + k);
            acc[nt] = __builtin_amdgcn_mfma_f32_16x16x32_bf16(af, bf, acc[nt], 0, 0, 0);
        }
    }
    const int mrow = (l >> 4) * 4;
#pragma unroll
    for (int nt = 0; nt < 4; ++nt) {
        int o = n0 + nt * 16 + l16;
        float bb = bout[o];
#pragma unroll
        for (int r = 0; r < 4; ++r) {
            out[(size_t)(m0 + mrow + r) * O_ + o] = acc[nt][r] + bb;
        }
    }
}

extern "C" void kernel_launch(void* const* d_in, const int* in_sizes, int n_in,
                              void* d_out, int out_size, void* d_ws, size_t ws_size,
                              hipStream_t stream) {
    const float* x     = (const float*)d_in[0];
    const float* W_ih  = (const float*)d_in[1];
    const float* W_hh  = (const float*)d_in[2];
    const float* b_ih  = (const float*)d_in[3];
    const float* b_hh  = (const float*)d_in[4];
    const float* W_out = (const float*)d_in[5];
    const float* b_out = (const float*)d_in[6];
    float* out = (float*)d_out;

    char* ws = (char*)d_ws;
    // ws layout (16B-aligned regions), total ~90.8 MB
    unsigned short* hs   = (unsigned short*)(ws);                         // 67,108,864 B
    float*          cst  = (float*)         (ws + 67108864);              //    262,144 B
    unsigned short* xbf  = (unsigned short*)(ws + 67371008);              // 16,777,216 B
    unsigned short* whh  = (unsigned short*)(ws + 84148224);              //  8,388,608 B
    unsigned short* wih  = (unsigned short*)(ws + 92536832);              //  2,097,152 B
    unsigned short* wout = (unsigned short*)(ws + 94633984);              //    524,288 B
    float*          bsum = (float*)         (ws + 95158272);              //     16,384 B

    cvt_bf16<<<2048, 256, 0, stream>>>(x,     xbf,  T_ * B_ * I_);
    cvt_bf16<<<2048, 256, 0, stream>>>(W_hh,  whh,  G4_ * H_);
    cvt_bf16<<<1024, 256, 0, stream>>>(W_ih,  wih,  G4_ * I_);
    cvt_bf16<<<256,  256, 0, stream>>>(W_out, wout, O_ * H_);
    bias_sum_k<<<16, 256, 0, stream>>>(b_ih, b_hh, bsum, G4_);

    for (int t = 0; t < T_; ++t) {
        lstm_step<<<128, 256, 0, stream>>>(xbf, whh, wih, bsum, hs, cst, t);
    }

    out_gemm<<<2048, 256, 0, stream>>>(hs, wout, b_out, out);
}